// Round 8
// baseline (217.634 us; speedup 1.0000x reference)
//
#include <hip/hip_runtime.h>

// GGNN on MI355X. N=100000, E=1000000, H=M=64, C=16.
// R7 post-mortem: k_mm stuck at ~67us — latency-bound, 75% stall; batching
// loads raised VGPR/AGPR and halved occupancy (38->17%). R8: eliminate k_mm.
// Algebra: gi = agg@Wih^T = S1@(Wih W0)^T + S0@(Wih W1)^T + c1*(Wih b0)
//          + c0*(Wih b1) + bih  -> precompute Wf0/Wf1 (k_wf), fuse the whole
// GRU+head MFMA tail into the gather kernel (k_gm). agg/s1b/s0b buffers and
// their 51MB round trip are gone; sH reuses the wave's dead CSR rows in LDS.
// Pipeline: k_init -> k_wf -> k_s1 -> k_s2 -> k_s3 -> k_gm.

typedef __bf16 bf16x8 __attribute__((ext_vector_type(8)));
typedef float  f32x4  __attribute__((ext_vector_type(4)));
typedef int    i32x4  __attribute__((ext_vector_type(4)));

#define MFMA16 __builtin_amdgcn_mfma_f32_16x16x32_bf16
#define NN   100000
#define EE   1000000
#define BB   782     // buckets (dst >> 7)
#define NPB  128     // nodes per bucket
#define ECAP 1600    // bucket region capacity (mean 1280, +9 sigma)
#define DCAP 48      // per-node degree cap (Poisson(10), P(>=48) ~ 1e-17)
#define CSTRD 49     // CSR LDS stride (ints)
#define NB   245     // histogram blocks (4096 edges each)
// wbn offsets (bf16 elems): Wf0 0, Wf1 12288, Whh 24576, Wout 36864
#define OWF1 12288
#define OWHH 24576
#define OWOUT 36864

__device__ __forceinline__ float sigmoidf_(float x) {
    return 1.0f / (1.0f + __expf(-x));
}
__device__ __forceinline__ float tanhf_(float x) {
    return 1.0f - 2.0f / (__expf(2.0f * x) + 1.0f);  // exact +/-inf limits
}

// ---- fused init: dtype detect / Whh+Wout cvt / feature cvt ----
__global__ __launch_bounds__(256) void k_init(const unsigned char* __restrict__ et,
                                              const float* __restrict__ feat,
                                              const float* __restrict__ whh,
                                              const float* __restrict__ wout,
                                              __bf16* __restrict__ featb,
                                              __bf16* __restrict__ wbn,
                                              int* __restrict__ flag) {
    int b = blockIdx.x, tid = threadIdx.x;
    if (b == 0) {
        // flag=1 iff any nonzero byte at offset%4!=0 in first 64KB (bool
        // storage); int32 0/1 storage has bytes 1..3 of every word zero.
        __shared__ int sdet[4];
        const i32x4* p = (const i32x4*)et + tid * 16;  // 256 B per thread
        unsigned acc = 0;
#pragma unroll
        for (int j = 0; j < 16; j++) {
            i32x4 w = p[j];
            acc |= (unsigned)(w[0] | w[1] | w[2] | w[3]) & 0xffffff00u;
        }
        unsigned long long m = __ballot(acc != 0);
        if ((tid & 63) == 0) sdet[tid >> 6] = (m != 0ULL);
        __syncthreads();
        if (tid == 0) *flag = sdet[0] | sdet[1] | sdet[2] | sdet[3];
        return;
    }
    if (b < 53) {  // 52 blocks * 256 = 13312 = Whh(12288) + Wout(1024)
        int i = (b - 1) * 256 + tid;
        if (i < 12288)      wbn[OWHH + i]          = (__bf16)whh[i];
        else                wbn[OWOUT + i - 12288] = (__bf16)wout[i - 12288];
        return;
    }
    long i = ((long)(b - 53) * 256 + tid) * 4;
    if (i >= (long)NN * 64) return;
    f32x4 v = *(const f32x4*)(feat + i);
    union { __bf16 e[4]; unsigned long long u; } o;
#pragma unroll
    for (int j = 0; j < 4; j++) o.e[j] = (__bf16)v[j];
    *(unsigned long long*)(featb + i) = o.u;
}

// ---- Wf0 = Wih@W0, Wf1 = Wih@W1 (bf16), bv0 = Wih@b0, bv1 = Wih@b1 (fp32)
__global__ __launch_bounds__(256) void k_wf(const float* __restrict__ wih,
                                            const float* __restrict__ w0,
                                            const float* __restrict__ w1,
                                            const float* __restrict__ b0,
                                            const float* __restrict__ b1,
                                            __bf16* __restrict__ wbn,
                                            float* __restrict__ bv0,
                                            float* __restrict__ bv1) {
    int idx = blockIdx.x * 256 + threadIdx.x;
    if (idx < 12288) {                 // Wf0[g][h]
        int g = idx >> 6, h = idx & 63;
        float acc = 0.f;
#pragma unroll 8
        for (int m = 0; m < 64; m++) acc += wih[g * 64 + m] * w0[m * 64 + h];
        wbn[idx] = (__bf16)acc;
    } else if (idx < 24576) {          // Wf1[g][h]
        int j = idx - 12288;
        int g = j >> 6, h = j & 63;
        float acc = 0.f;
#pragma unroll 8
        for (int m = 0; m < 64; m++) acc += wih[g * 64 + m] * w1[m * 64 + h];
        wbn[idx] = (__bf16)acc;
    } else if (idx < 24768) {          // bv0[g], bv1[g]
        int g = idx - 24576;
        float a0 = 0.f, a1 = 0.f;
#pragma unroll 8
        for (int m = 0; m < 64; m++) {
            float w = wih[g * 64 + m];
            a0 += w * b0[m];
            a1 += w * b1[m];
        }
        bv0[g] = a0;
        bv1[g] = a1;
    }
}

// ---- s1: per-block bucket histogram (LDS non-returning atomics only) ----
__global__ __launch_bounds__(512) void k_s1(const int* __restrict__ dst,
                                            int* __restrict__ hist) {
    __shared__ int cnt[BB];
    int blk = blockIdx.x, tid = threadIdx.x;
    for (int i = tid; i < BB; i += 512) cnt[i] = 0;
    __syncthreads();
    long e0 = (long)blk * 4096 + tid * 8;  // EE % 8 == 0: no scalar tail
    if (e0 < EE) {
        i32x4 d0 = *(const i32x4*)(dst + e0);
        i32x4 d1 = *(const i32x4*)(dst + e0 + 4);
#pragma unroll
        for (int j = 0; j < 4; j++) atomicAdd(&cnt[d0[j] >> 7], 1);
#pragma unroll
        for (int j = 0; j < 4; j++) atomicAdd(&cnt[d1[j] >> 7], 1);
    }
    __syncthreads();
    for (int i = tid; i < BB; i += 512) hist[blk * BB + i] = cnt[i];
}

// ---- s2: exclusive scan over blocks per bucket (1 wave/bucket) ----
__global__ __launch_bounds__(256) void k_s2(const int* __restrict__ hist,
                                            int* __restrict__ blockBase,
                                            int* __restrict__ bucketCnt) {
    int b = blockIdx.x * 4 + (threadIdx.x >> 6);
    int lane = threadIdx.x & 63;
    if (b >= BB) return;
    int carry = 0;
    for (int c = 0; c < 4; c++) {       // ceil(245/64) = 4 chunks
        int blk = c * 64 + lane;
        int v = (blk < NB) ? hist[blk * BB + b] : 0;
        int x = v;
#pragma unroll
        for (int off = 1; off < 64; off <<= 1) {
            int y = __shfl_up(x, off, 64);
            if (lane >= off) x += y;
        }
        if (blk < NB) blockBase[blk * BB + b] = x - v + carry;
        carry += __shfl(x, 63, 64);
    }
    if (lane == 0) bucketCnt[b] = carry;
}

// ---- s3: place edges deterministically (LDS cursors seeded w/ blockBase) ----
__global__ __launch_bounds__(512) void k_s3(const int* __restrict__ src,
                                            const int* __restrict__ dst,
                                            const unsigned char* __restrict__ etype,
                                            const int* __restrict__ flag,
                                            const int* __restrict__ blockBase,
                                            int* __restrict__ region) {
    __shared__ int cur[BB];
    int blk = blockIdx.x, tid = threadIdx.x;
    for (int i = tid; i < BB; i += 512) cur[i] = blockBase[blk * BB + i];
    __syncthreads();
    long e0 = (long)blk * 4096 + tid * 8;
    if (e0 >= EE) return;
    i32x4 s0 = *(const i32x4*)(src + e0);
    i32x4 s1 = *(const i32x4*)(src + e0 + 4);
    i32x4 d0 = *(const i32x4*)(dst + e0);
    i32x4 d1 = *(const i32x4*)(dst + e0 + 4);
    int t[8];
    if (*flag) {  // 1-byte bool storage
        unsigned long long w = *(const unsigned long long*)(etype + e0);
#pragma unroll
        for (int j = 0; j < 8; j++) t[j] = (int)((w >> (8 * j)) & 0xff);
    } else {      // int32 storage
        i32x4 w0 = *(const i32x4*)((const int*)etype + e0);
        i32x4 w1 = *(const i32x4*)((const int*)etype + e0 + 4);
#pragma unroll
        for (int j = 0; j < 4; j++) { t[j] = w0[j]; t[4 + j] = w1[j]; }
    }
    int dd[8] = {d0[0], d0[1], d0[2], d0[3], d1[0], d1[1], d1[2], d1[3]};
    int ss[8] = {s0[0], s0[1], s0[2], s0[3], s1[0], s1[1], s1[2], s1[3]};
#pragma unroll
    for (int j = 0; j < 8; j++) {
        int b  = dd[j] >> 7;
        int nl = dd[j] & 127;
        int r  = atomicAdd(&cur[b], 1);  // LDS returning atomic: fast
        if (r < ECAP)
            region[b * ECAP + r] = (nl << 18) | ((t[j] ? 1 : 0) << 17) | ss[j];
    }
}

// ---- fused gather + GRU + head. One block = one bucket (128 nodes, 8 waves,
// 16 nodes/wave). Gather sums land in registers in MFMA A-frag layout; the
// MFMA tail runs on in-register data + L2-hot weights; sH reuses the wave's
// own dead CSR rows (wave-private after gather; same-wave LDS is in-order).
__global__ __launch_bounds__(512) void k_gm(const __bf16* __restrict__ featb,
                                            const int* __restrict__ region,
                                            const int* __restrict__ bucketCnt,
                                            const __bf16* __restrict__ wbn,
                                            const float* __restrict__ bv0,
                                            const float* __restrict__ bv1,
                                            const float* __restrict__ bih,
                                            const float* __restrict__ bhh,
                                            const float* __restrict__ bout,
                                            float* __restrict__ out) {
    __shared__ int ncnt[NPB];
    __shared__ __align__(16) int csr[NPB * CSTRD];
    int b = blockIdx.x, tid = threadIdx.x;
    int cntE = min(bucketCnt[b], ECAP);
    if (tid < NPB) ncnt[tid] = 0;
    __syncthreads();
    const int* reg = region + b * ECAP;
    for (int i = tid; i < cntE; i += 512) {
        int rec = reg[i];
        int nl = rec >> 18;
        int r = atomicAdd(&ncnt[nl], 1);
        if (r < DCAP) csr[nl * CSTRD + r] = rec & 0x3ffff;  // type|src
    }
    __syncthreads();

    int lane = tid & 63, wave = tid >> 6;
    int L = lane & 15, q = lane >> 4;
    int nl = wave * 16 + L;        // 8 waves x 16 nodes = 128
    int n0 = b * NPB + wave * 16;
    int n = n0 + L;
    int cnt = min(ncnt[nl], DCAP);
    const int* eb = &csr[nl * CSTRD];

    // ===== gather: fp32 type-split sums in A-frag layout =====
    float sA[16], s1[16];
#pragma unroll
    for (int j = 0; j < 16; j++) { sA[j] = 0.f; s1[j] = 0.f; }
    int c1 = 0;
    int i = 0;
    for (; i + 4 <= cnt; i += 4) {  // x4: 8 outstanding 16B gathers per trip
        int e4[4];
#pragma unroll
        for (int j = 0; j < 4; j++) e4[j] = eb[i + j];
        bf16x8 ra[4], rb[4];
#pragma unroll
        for (int j = 0; j < 4; j++) {
            const __bf16* row = featb + (long)(e4[j] & 0x1ffff) * 64;
            ra[j] = *(const bf16x8*)(row + q * 8);
            rb[j] = *(const bf16x8*)(row + 32 + q * 8);
        }
#pragma unroll
        for (int j = 0; j < 4; j++) {
            int t = (e4[j] >> 17) & 1;
            c1 += t;
            float ft = (float)t;
#pragma unroll
            for (int k = 0; k < 8; k++) {
                float va = (float)ra[j][k], wa = (float)rb[j][k];
                sA[k]     += va;       sA[8 + k] += wa;
                s1[k]     += ft * va;  s1[8 + k] += ft * wa;
            }
        }
    }
    for (; i < cnt; i++) {
        int ea = eb[i];
        const __bf16* row = featb + (long)(ea & 0x1ffff) * 64;
        bf16x8 a0 = *(const bf16x8*)(row + q * 8);
        bf16x8 a1 = *(const bf16x8*)(row + 32 + q * 8);
        int ta = (ea >> 17) & 1;
        c1 += ta;
        float fa = (float)ta;
#pragma unroll
        for (int k = 0; k < 8; k++) {
            float va = (float)a0[k], wa = (float)a1[k];
            sA[k] += va;          sA[8 + k] += wa;
            s1[k] += fa * va;     s1[8 + k] += fa * wa;
        }
    }

    // ===== A-frags =====
    bf16x8 AS1[2], AS0[2];
#pragma unroll
    for (int ch = 0; ch < 2; ch++) {
        union { bf16x8 v; __bf16 e[8]; } u0, u1;
#pragma unroll
        for (int j = 0; j < 8; j++) {
            float v1 = s1[ch * 8 + j];
            u1.e[j] = (__bf16)v1;
            u0.e[j] = (__bf16)(sA[ch * 8 + j] - v1);
        }
        AS1[ch] = u1.v;
        AS0[ch] = u0.v;
    }
    long fn = (n < NN) ? n : (NN - 1);
    const __bf16* fr = featb + fn * 64;
    bf16x8 Aft[2] = { *(const bf16x8*)(fr + q * 8), *(const bf16x8*)(fr + 32 + q * 8) };

    // counts for D-layout rows (node m = q*4+r held by lane m)
    float fc1[4], fc0[4];
#pragma unroll
    for (int r = 0; r < 4; r++) {
        int m = q * 4 + r;
        int c1m = __shfl(c1, m);
        int cm  = __shfl(cnt, m);
        fc1[r] = (float)c1m;
        fc0[r] = (float)(cm - c1m);
    }

    // sH reuses this wave's dead CSR rows (3136B >= 16*80*2 = 2560B)
    __bf16* sH = (__bf16*)&csr[wave * 16 * CSTRD];

    const __bf16* wf0 = wbn, * wf1 = wbn + OWF1, * whb = wbn + OWHH;
    f32x4 zz = {0.f, 0.f, 0.f, 0.f};

#pragma unroll
    for (int nb = 0; nb < 4; nb++) {
        int ro = (nb * 16 + L) * 64 + q * 8;
        // gate r: gi_r + gh_r fused into one accumulator
        f32x4 aR = zz, aZ = zz, aIN = zz, aHN = zz;
        {
            bf16x8 W[6] = { *(const bf16x8*)(wf0 + ro), *(const bf16x8*)(wf0 + ro + 32),
                            *(const bf16x8*)(wf1 + ro), *(const bf16x8*)(wf1 + ro + 32),
                            *(const bf16x8*)(whb + ro), *(const bf16x8*)(whb + ro + 32) };
            aR = MFMA16(AS1[0], W[0], aR, 0, 0, 0);
            aR = MFMA16(AS1[1], W[1], aR, 0, 0, 0);
            aR = MFMA16(AS0[0], W[2], aR, 0, 0, 0);
            aR = MFMA16(AS0[1], W[3], aR, 0, 0, 0);
            aR = MFMA16(Aft[0], W[4], aR, 0, 0, 0);
            aR = MFMA16(Aft[1], W[5], aR, 0, 0, 0);
        }
        {
            int rz = ro + 4096;  // +64 rows
            bf16x8 W[6] = { *(const bf16x8*)(wf0 + rz), *(const bf16x8*)(wf0 + rz + 32),
                            *(const bf16x8*)(wf1 + rz), *(const bf16x8*)(wf1 + rz + 32),
                            *(const bf16x8*)(whb + rz), *(const bf16x8*)(whb + rz + 32) };
            aZ = MFMA16(AS1[0], W[0], aZ, 0, 0, 0);
            aZ = MFMA16(AS1[1], W[1], aZ, 0, 0, 0);
            aZ = MFMA16(AS0[0], W[2], aZ, 0, 0, 0);
            aZ = MFMA16(AS0[1], W[3], aZ, 0, 0, 0);
            aZ = MFMA16(Aft[0], W[4], aZ, 0, 0, 0);
            aZ = MFMA16(Aft[1], W[5], aZ, 0, 0, 0);
        }
        {
            int rn = ro + 8192;  // +128 rows
            bf16x8 W[6] = { *(const bf16x8*)(wf0 + rn), *(const bf16x8*)(wf0 + rn + 32),
                            *(const bf16x8*)(wf1 + rn), *(const bf16x8*)(wf1 + rn + 32),
                            *(const bf16x8*)(whb + rn), *(const bf16x8*)(whb + rn + 32) };
            aIN = MFMA16(AS1[0], W[0], aIN, 0, 0, 0);
            aIN = MFMA16(AS1[1], W[1], aIN, 0, 0, 0);
            aIN = MFMA16(AS0[0], W[2], aIN, 0, 0, 0);
            aIN = MFMA16(AS0[1], W[3], aIN, 0, 0, 0);
            aHN = MFMA16(Aft[0], W[4], aHN, 0, 0, 0);
            aHN = MFMA16(Aft[1], W[5], aHN, 0, 0, 0);
        }
        // biases (per-lane scalars, gate rows nb*16+L)
        int gr = nb * 16 + L;
        float bvr0 = bv0[gr],       bvr1 = bv1[gr];
        float bvz0 = bv0[64 + gr],  bvz1 = bv1[64 + gr];
        float bvn0 = bv0[128 + gr], bvn1 = bv1[128 + gr];
        float brz = bih[gr] + bhh[gr];
        float bzz = bih[64 + gr] + bhh[64 + gr];
        float bin = bih[128 + gr];
        float bhn = bhh[128 + gr];
        // blend values (D-layout) from warm featb
        float fvv[4];
#pragma unroll
        for (int r = 0; r < 4; r++) {
            long node = n0 + q * 4 + r;
            if (node >= NN) node = NN - 1;
            fvv[r] = (float)featb[node * 64 + gr];
        }
#pragma unroll
        for (int r = 0; r < 4; r++) {
            float rv = sigmoidf_(aR[r] + fc1[r] * bvr0 + fc0[r] * bvr1 + brz);
            float zv = sigmoidf_(aZ[r] + fc1[r] * bvz0 + fc0[r] * bvz1 + bzz);
            float iv = aIN[r] + fc1[r] * bvn0 + fc0[r] * bvn1 + bin;
            float nv = tanhf_(iv + rv * (aHN[r] + bhn));
            float hv = (1.0f - zv) * nv + zv * fvv[r];
            sH[(q * 4 + r) * 80 + gr] = (__bf16)hv;
        }
    }

    // ===== head: out = h @ W_out^T + b_out =====
    bf16x8 Ah0 = *(const bf16x8*)&sH[L * 80 + q * 8];
    bf16x8 Ah1 = *(const bf16x8*)&sH[L * 80 + 32 + q * 8];
    const __bf16* wo = wbn + OWOUT;
    bf16x8 Bo0 = *(const bf16x8*)(wo + L * 64 + q * 8);
    bf16x8 Bo1 = *(const bf16x8*)(wo + L * 64 + 32 + q * 8);
    f32x4 o = zz;
    o = MFMA16(Ah0, Bo0, o, 0, 0, 0);
    o = MFMA16(Ah1, Bo1, o, 0, 0, 0);
    float bo = bout[L];
#pragma unroll
    for (int r = 0; r < 4; r++) {
        long node = n0 + q * 4 + r;
        if (node < NN) out[node * 16 + L] = o[r] + bo;
    }
}

extern "C" void kernel_launch(void* const* d_in, const int* in_sizes, int n_in,
                              void* d_out, int out_size, void* d_ws, size_t ws_size,
                              hipStream_t stream) {
    const float* features = (const float*)d_in[0];
    const int*   src      = (const int*)d_in[1];
    const int*   dst      = (const int*)d_in[2];
    const unsigned char* etype = (const unsigned char*)d_in[3];
    const float* W0   = (const float*)d_in[4];
    const float* b0   = (const float*)d_in[5];
    const float* W1   = (const float*)d_in[6];
    const float* b1   = (const float*)d_in[7];
    const float* Wih  = (const float*)d_in[8];
    const float* Whh  = (const float*)d_in[9];
    const float* bih  = (const float*)d_in[10];
    const float* bhh  = (const float*)d_in[11];
    const float* Wout = (const float*)d_in[12];
    const float* bout = (const float*)d_in[13];
    float* out = (float*)d_out;

    char* ws = (char*)d_ws;
    size_t off = 0;
    __bf16* featb     = (__bf16*)(ws + off); off += (size_t)NN * 64 * 2;     // 12.8 MB
    int*    region    = (int*)(ws + off);    off += (size_t)BB * ECAP * 4;   // 5.0 MB
    int*    hist      = (int*)(ws + off);    off += (size_t)NB * BB * 4;     // 766 KB
    int*    blockBase = (int*)(ws + off);    off += (size_t)NB * BB * 4;     // 766 KB
    int*    bucketCnt = (int*)(ws + off);    off += (size_t)BB * 4;
    __bf16* wbn       = (__bf16*)(ws + off); off += 37888 * 2;
    float*  bv0       = (float*)(ws + off);  off += 192 * 4;
    float*  bv1       = (float*)(ws + off);  off += 192 * 4;
    int*    flag      = (int*)(ws + off);

    k_init<<<6303, 256, 0, stream>>>(etype, features, Whh, Wout, featb, wbn, flag);
    k_wf<<<97, 256, 0, stream>>>(Wih, W0, W1, b0, b1, wbn, bv0, bv1);
    k_s1<<<NB, 512, 0, stream>>>(dst, hist);
    k_s2<<<(BB + 3) / 4, 256, 0, stream>>>(hist, blockBase, bucketCnt);
    k_s3<<<NB, 512, 0, stream>>>(src, dst, etype, flag, blockBase, region);
    k_gm<<<BB, 512, 0, stream>>>(featb, region, bucketCnt, wbn, bv0, bv1,
                                 bih, bhh, bout, out);
}